// Round 20
// baseline (6231.318 us; speedup 1.0000x reference)
//
#include <hip/hip_runtime.h>

typedef __attribute__((ext_vector_type(8))) short short8;
typedef __attribute__((ext_vector_type(4))) float f32x4;
typedef __attribute__((ext_vector_type(4))) unsigned u32x4;

__device__ __forceinline__ unsigned short f2bf(float f) {
  unsigned int u = __float_as_uint(f);
  u = (u + 0x7fffu + ((u >> 16) & 1u)) >> 16;
  return (unsigned short)u;
}

__device__ __forceinline__ void xp_store(float* p, float v) { *p = v; }
__device__ __forceinline__ void xp_store(unsigned short* p, float v) { *p = f2bf(v); }
__device__ __forceinline__ float xp_ld(const float* p) { return *p; }
__device__ __forceinline__ float xp_ld(const unsigned short* p) {
  return __uint_as_float(((unsigned int)*p) << 16);
}

// quad reduce via DPP (VALU pipe, no DS): sum over the 4 lanes of each quad.
__device__ __forceinline__ float quad_sum(float a) {
  float t1 = __int_as_float(
      __builtin_amdgcn_update_dpp(0, __float_as_int(a), 177, 0xf, 0xf, true));
  a += t1;
  float t2 = __int_as_float(
      __builtin_amdgcn_update_dpp(0, __float_as_int(a), 78, 0xf, 0xf, true));
  return a + t2;
}

// ---------------- prep: pack W_x and W_h (f32 -> bf16 pairs) ----------------
__global__ void prep_wx(const float* __restrict__ W, unsigned int* __restrict__ Wx2) {
  int i = blockIdx.x * 256 + threadIdx.x;  // 1024*128 dwords
  int g = i >> 7, kk = i & 127;
  float lo = W[(size_t)g * 512 + 256 + 2 * kk];
  float hi = W[(size_t)g * 512 + 256 + 2 * kk + 1];
  Wx2[i] = (unsigned int)f2bf(lo) | ((unsigned int)f2bf(hi) << 16);
}

__global__ void prep_wh(const float* __restrict__ W, unsigned int* __restrict__ Wh2) {
  int i = blockIdx.x * 256 + threadIdx.x;  // 1024*128 dwords
  int r = i >> 7, kk = i & 127;
  float lo = W[(size_t)r * 512 + 2 * kk];
  float hi = W[(size_t)r * 512 + 2 * kk + 1];
  Wh2[i] = (unsigned int)f2bf(lo) | ((unsigned int)f2bf(hi) << 16);
}

// ---------------- GEMM: xp[m][g] = sum_k x[m][k] * Wx[g][k] + b[g] ----------------
template <typename XPT>
__global__ __launch_bounds__(256, 4) void gemm_xp(const float* __restrict__ x,
                                                  const unsigned int* __restrict__ Wx2,
                                                  const float* __restrict__ bias,
                                                  XPT* __restrict__ xp) {
  __shared__ unsigned short As[128][40];
  __shared__ unsigned short Bs[128][40];
  const int m0 = blockIdx.y * 128, n0 = blockIdx.x * 128;
  const int tid = threadIdx.x, lane = tid & 63, w = tid >> 6;
  const int wr = w >> 1, wc = w & 1;
  const int r16 = lane & 15, kq = lane >> 4;
  f32x4 acc[4][4];
#pragma unroll
  for (int m = 0; m < 4; m++)
#pragma unroll
    for (int n = 0; n < 4; n++)
#pragma unroll
      for (int j = 0; j < 4; j++) acc[m][n][j] = 0.f;

  for (int kb = 0; kb < 256; kb += 32) {
    __syncthreads();
#pragma unroll
    for (int i = 0; i < 4; i++) {
      int idx = tid + i * 256;
      int row = idx >> 3, c4 = idx & 7;
      float4 v = *(const float4*)(x + (size_t)(m0 + row) * 256 + kb + c4 * 4);
      ushort4 s;
      s.x = f2bf(v.x); s.y = f2bf(v.y); s.z = f2bf(v.z); s.w = f2bf(v.w);
      *(ushort4*)&As[row][c4 * 4] = s;
    }
#pragma unroll
    for (int i = 0; i < 2; i++) {
      int idx = tid + i * 256;
      int row = idx >> 2, c = idx & 3;
      uint4 v = *(const uint4*)(Wx2 + (size_t)(n0 + row) * 128 + (kb >> 1) + c * 4);
      *(uint4*)&Bs[row][c * 8] = v;
    }
    __syncthreads();
    short8 a[4], bb[4];
#pragma unroll
    for (int m = 0; m < 4; m++)
      a[m] = *(const short8*)&As[wr * 64 + m * 16 + r16][kq * 8];
#pragma unroll
    for (int n = 0; n < 4; n++)
      bb[n] = *(const short8*)&Bs[wc * 64 + n * 16 + r16][kq * 8];
#pragma unroll
    for (int m = 0; m < 4; m++)
#pragma unroll
      for (int n = 0; n < 4; n++)
        acc[m][n] = __builtin_amdgcn_mfma_f32_16x16x32_bf16(a[m], bb[n], acc[m][n], 0, 0, 0);
  }
#pragma unroll
  for (int n = 0; n < 4; n++) {
    int gn = n0 + wc * 64 + n * 16 + r16;
    float bi = bias[gn];
#pragma unroll
    for (int m = 0; m < 4; m++) {
      int gm = m0 + wr * 64 + m * 16 + kq * 4;
#pragma unroll
      for (int j = 0; j < 4; j++) {
        xp_store(&xp[(size_t)(gm + j) * 1024 + gn], acc[m][n][j] + bi);
      }
    }
  }
}

// ---------------- recurrence: 512 threads x 256-reg budget, 2 units/thread ---------
// R16/R19 structure (verified 2016us) with ONE change: the o-rows stream from
// GLOBAL/L2 instead of LDS. Arithmetic: per CU per step the DS pipe ran 192
// ds_read_b128 (~12cy each, m134) ~ 2300cy -- half the 4725cy step -- while the VMEM
// pipe sat idle (HBM 0.9%). Each CU's o-slice is 128KB (1MB/XCD L2, pure L2 traffic
// at ~64GB/s/CU). Plain loads: at this register pressure the compiler provably
// rematerializes them per-iteration (R8), giving the desired per-step streaming with
// NO manual vmcnt counting (the R18 failure mode). DS traffic 24->8 b128/thr/step;
// depth-2 rotation retained so ~200cy L2 latency hides under the previous chunk's
// 32 dot2s. Same oA_p/oB_p + (E<<2) addresses the old staging loop used.
// TELLS: LDS_Block_Size ~4.6KB; FETCH stays ~67MB (o re-reads are L2, not HBM).
// h: bf16 pairs, 2 slots x 4 p-copies stride 136 (conflict-free); DPP quad reduce;
// raw barrier {lgkmcnt(0); s_barrier}; xp direct from global.
template <typename XPT>
__global__ __attribute__((amdgpu_flat_work_group_size(512, 512),
                          amdgpu_waves_per_eu(2, 2)))
void lstm_rec(const unsigned* __restrict__ Wh2,
              const XPT* __restrict__ xp,
              float* __restrict__ out) {
  __shared__ unsigned hsh[2][4][136];      // 4352B: h bf16-pairs, 2 slots x 4 p-copies

  const int tid = threadIdx.x;
  const int b = blockIdx.x;
  const int v = tid >> 2, p = tid & 3;
  const int brow0 = b << 10;

  // ---- weight register loads: f,i,g rows of units v and v+128 (192 dwords)
  const unsigned* fA_p = Wh2 + (size_t)(v) * 128 + (p << 5);
  const unsigned* iA_p = Wh2 + (size_t)(256 + v) * 128 + (p << 5);
  const unsigned* gA_p = Wh2 + (size_t)(512 + v) * 128 + (p << 5);
  const unsigned* oA_p = Wh2 + (size_t)(768 + v) * 128 + (p << 5);
  const unsigned* fB_p = Wh2 + (size_t)(128 + v) * 128 + (p << 5);
  const unsigned* iB_p = Wh2 + (size_t)(384 + v) * 128 + (p << 5);
  const unsigned* gB_p = Wh2 + (size_t)(640 + v) * 128 + (p << 5);
  const unsigned* oB_p = Wh2 + (size_t)(896 + v) * 128 + (p << 5);
  u32x4 fA0, fA1, fA2, fA3, fA4, fA5, fA6, fA7;
  u32x4 iA0, iA1, iA2, iA3, iA4, iA5, iA6, iA7;
  u32x4 gA0, gA1, gA2, gA3, gA4, gA5, gA6, gA7;
  u32x4 fB0, fB1, fB2, fB3, fB4, fB5, fB6, fB7;
  u32x4 iB0, iB1, iB2, iB3, iB4, iB5, iB6, iB7;
  u32x4 gB0, gB1, gB2, gB3, gB4, gB5, gB6, gB7;
#define LOADROW8(P, R0, R1, R2, R3, R4, R5, R6, R7)                   \
  asm volatile("global_load_dwordx4 %0, %8, off\n\t"                  \
               "global_load_dwordx4 %1, %8, off offset:16\n\t"        \
               "global_load_dwordx4 %2, %8, off offset:32\n\t"        \
               "global_load_dwordx4 %3, %8, off offset:48\n\t"        \
               "global_load_dwordx4 %4, %8, off offset:64\n\t"        \
               "global_load_dwordx4 %5, %8, off offset:80\n\t"        \
               "global_load_dwordx4 %6, %8, off offset:96\n\t"        \
               "global_load_dwordx4 %7, %8, off offset:112"           \
               : "=&v"(R0), "=&v"(R1), "=&v"(R2), "=&v"(R3),          \
                 "=&v"(R4), "=&v"(R5), "=&v"(R6), "=&v"(R7)           \
               : "v"(P)                                               \
               : "memory")
  LOADROW8(fA_p, fA0, fA1, fA2, fA3, fA4, fA5, fA6, fA7);
  LOADROW8(iA_p, iA0, iA1, iA2, iA3, iA4, iA5, iA6, iA7);
  LOADROW8(gA_p, gA0, gA1, gA2, gA3, gA4, gA5, gA6, gA7);
  LOADROW8(fB_p, fB0, fB1, fB2, fB3, fB4, fB5, fB6, fB7);
  LOADROW8(iB_p, iB0, iB1, iB2, iB3, iB4, iB5, iB6, iB7);
  LOADROW8(gB_p, gB0, gB1, gB2, gB3, gB4, gB5, gB6, gB7);
#undef LOADROW8
  asm volatile("s_waitcnt vmcnt(0)" ::: "memory");

  // ---- zero both h slots
  for (int i = tid; i < 2 * 4 * 136; i += 512) ((unsigned*)hsh)[i] = 0u;
  float c0 = 0.f, c1 = 0.f;
  float* outp = out + ((size_t)brow0 << 8);
  __syncthreads();  // one full barrier before the loop (covers LDS init)

#define BAR() asm volatile("s_waitcnt lgkmcnt(0)\n\ts_barrier" ::: "memory")
#define DOT2(ACC, WD, HD) \
  asm("v_dot2_f32_bf16 %0, %1, %2, %0" : "+v"(ACC) : "v"(WD), "v"(HD))
// dot one chunk: 2 units x 4 gates x 4 dwords = 32 dot2, all register operands
#define DOTC(FA, IA, GA, FB, IB, GB, OA, OB, HJ)                    \
  {                                                                 \
    DOT2(aF0, FA[0], (HJ)[0]); DOT2(aF0, FA[1], (HJ)[1]);           \
    DOT2(aF0, FA[2], (HJ)[2]); DOT2(aF0, FA[3], (HJ)[3]);           \
    DOT2(aI0, IA[0], (HJ)[0]); DOT2(aI0, IA[1], (HJ)[1]);           \
    DOT2(aI0, IA[2], (HJ)[2]); DOT2(aI0, IA[3], (HJ)[3]);           \
    DOT2(aG0, GA[0], (HJ)[0]); DOT2(aG0, GA[1], (HJ)[1]);           \
    DOT2(aG0, GA[2], (HJ)[2]); DOT2(aG0, GA[3], (HJ)[3]);           \
    DOT2(aO0, (OA)[0], (HJ)[0]); DOT2(aO0, (OA)[1], (HJ)[1]);       \
    DOT2(aO0, (OA)[2], (HJ)[2]); DOT2(aO0, (OA)[3], (HJ)[3]);       \
    DOT2(aF1, FB[0], (HJ)[0]); DOT2(aF1, FB[1], (HJ)[1]);           \
    DOT2(aF1, FB[2], (HJ)[2]); DOT2(aF1, FB[3], (HJ)[3]);           \
    DOT2(aI1, IB[0], (HJ)[0]); DOT2(aI1, IB[1], (HJ)[1]);           \
    DOT2(aI1, IB[2], (HJ)[2]); DOT2(aI1, IB[3], (HJ)[3]);           \
    DOT2(aG1, GB[0], (HJ)[0]); DOT2(aG1, GB[1], (HJ)[1]);           \
    DOT2(aG1, GB[2], (HJ)[2]); DOT2(aG1, GB[3], (HJ)[3]);           \
    DOT2(aO1, (OB)[0], (HJ)[0]); DOT2(aO1, (OB)[1], (HJ)[1]);       \
    DOT2(aO1, (OB)[2], (HJ)[2]); DOT2(aO1, (OB)[3], (HJ)[3]);       \
  }
#define HJC(HRX, J) (*(const u32x4*)&hsh[HRX][p][(p << 5) + ((J) << 2)])
#define OAC(J) (*(const u32x4*)(oA_p + ((J) << 2)))
#define OBC(J) (*(const u32x4*)(oB_p + ((J) << 2)))

#define LSTM1(AF, AI, AG, AO, X0, X1, X2, X3, CC, HOUT)             \
  {                                                                 \
    float gf = AF + X0, gi = AI + X1, gg = AG + X2, go = AO + X3;   \
    float f = 1.f / (1.f + __expf(-gf));                            \
    float ii = 1.f / (1.f + __expf(-gi));                           \
    float eg = __expf(2.f * gg);                                    \
    float gtv = (eg - 1.f) / (eg + 1.f);                            \
    float o = 1.f / (1.f + __expf(-go));                            \
    CC = f * CC + ii * gtv;                                         \
    float ec = __expf(2.f * CC);                                    \
    float tc = (ec - 1.f) / (ec + 1.f);                             \
    HOUT = o * tc;                                                  \
  }

#define STEP(T, HR, HW)                                                                \
  {                                                                                    \
    const int t = (T);                                                                 \
    /* xp for THIS step: direct global loads (VMEM pipe, consumed at gate add) */      \
    const XPT* xr = xp + ((size_t)(brow0 + t) << 10);                                  \
    float xv0 = xp_ld(xr + v),        xv1 = xp_ld(xr + 256 + v);                       \
    float xv2 = xp_ld(xr + 512 + v),  xv3 = xp_ld(xr + 768 + v);                       \
    float xw0 = xp_ld(xr + 128 + v),  xw1 = xp_ld(xr + 384 + v);                       \
    float xw2 = xp_ld(xr + 640 + v),  xw3 = xp_ld(xr + 896 + v);                       \
    /* depth-2 pipeline over chunks; o streams from L2 (VMEM), h from LDS (DS) */      \
    u32x4 hX = HJC(HR, 0), oAX = OAC(0), oBX = OBC(0);                                 \
    u32x4 hY = HJC(HR, 1), oAY = OAC(1), oBY = OBC(1);                                 \
    float aF0 = 0.f, aI0 = 0.f, aG0 = 0.f, aO0 = 0.f;                                  \
    float aF1 = 0.f, aI1 = 0.f, aG1 = 0.f, aO1 = 0.f;                                  \
    DOTC(fA0, iA0, gA0, fB0, iB0, gB0, oAX, oBX, hX)                                   \
    hX = HJC(HR, 2); oAX = OAC(2); oBX = OBC(2);                                       \
    DOTC(fA1, iA1, gA1, fB1, iB1, gB1, oAY, oBY, hY)                                   \
    hY = HJC(HR, 3); oAY = OAC(3); oBY = OBC(3);                                       \
    DOTC(fA2, iA2, gA2, fB2, iB2, gB2, oAX, oBX, hX)                                   \
    hX = HJC(HR, 4); oAX = OAC(4); oBX = OBC(4);                                       \
    DOTC(fA3, iA3, gA3, fB3, iB3, gB3, oAY, oBY, hY)                                   \
    hY = HJC(HR, 5); oAY = OAC(5); oBY = OBC(5);                                       \
    DOTC(fA4, iA4, gA4, fB4, iB4, gB4, oAX, oBX, hX)                                   \
    hX = HJC(HR, 6); oAX = OAC(6); oBX = OBC(6);                                       \
    DOTC(fA5, iA5, gA5, fB5, iB5, gB5, oAY, oBY, hY)                                   \
    hY = HJC(HR, 7); oAY = OAC(7); oBY = OBC(7);                                       \
    DOTC(fA6, iA6, gA6, fB6, iB6, gB6, oAX, oBX, hX)                                   \
    DOTC(fA7, iA7, gA7, fB7, iB7, gB7, oAY, oBY, hY)                                   \
    /* reduce over the 4 p-lanes: DPP quad_perm adds (VALU pipe, no DS) */             \
    aF0 = quad_sum(aF0); aI0 = quad_sum(aI0); aG0 = quad_sum(aG0); aO0 = quad_sum(aO0);\
    aF1 = quad_sum(aF1); aI1 = quad_sum(aI1); aG1 = quad_sum(aG1); aO1 = quad_sum(aO1);\
    float h0v, h1v;                                                                    \
    LSTM1(aF0, aI0, aG0, aO0, xv0, xv1, xv2, xv3, c0, h0v)                             \
    LSTM1(aF1, aI1, aG1, aO1, xw0, xw1, xw2, xw3, c1, h1v)                             \
    /* publish: each lane writes both units' bf16 into its own p-copy */               \
    ((unsigned short*)&hsh[HW][p][0])[v] = f2bf(h0v);                                  \
    ((unsigned short*)&hsh[HW][p][0])[v + 128] = f2bf(h1v);                            \
    if (p == 0) {                                                                      \
      __builtin_nontemporal_store(h0v, outp + ((size_t)t << 8) + v);                   \
      __builtin_nontemporal_store(h1v, outp + ((size_t)t << 8) + v + 128);             \
      if (t == 1023) {                                                                 \
        out[16777216 + b * 256 + v] = h0v;                                             \
        out[16777216 + b * 256 + v + 128] = h1v;                                       \
        out[16777216 + 16384 + b * 256 + v] = c0;                                      \
        out[16777216 + 16384 + b * 256 + v + 128] = c1;                                \
      }                                                                                \
    }                                                                                  \
    /* raw barrier: LDS ordering only -- no vmcnt drain of out-store/xp/o loads */     \
    BAR();                                                                             \
  }

  for (int t2 = 0; t2 < 1024; t2 += 2) {
    STEP(t2, 1, 0)      // t even: read h slot1, write slot0
    STEP(t2 + 1, 0, 1)  // t odd:  read h slot0, write slot1
  }
#undef STEP
#undef LSTM1
#undef HJC
#undef OAC
#undef OBC
#undef DOTC
#undef DOT2
#undef BAR
}

extern "C" void kernel_launch(void* const* d_in, const int* in_sizes, int n_in,
                              void* d_out, int out_size, void* d_ws, size_t ws_size,
                              hipStream_t stream) {
  (void)in_sizes; (void)n_in; (void)out_size;
  const float* x = (const float*)d_in[0];
  const float* W = (const float*)d_in[1];
  const float* bias = (const float*)d_in[2];
  float* out = (float*)d_out;
  char* ws = (char*)d_ws;

  unsigned int* Wx2 = (unsigned int*)ws;              // 524288 B
  unsigned int* Wh2 = (unsigned int*)(ws + 524288);   // 524288 B
  char* xpmem = ws + 1048576;

  const size_t need32 = 1048576 + (size_t)65536 * 1024 * 4;

  prep_wx<<<512, 256, 0, stream>>>(W, Wx2);
  prep_wh<<<512, 256, 0, stream>>>(W, Wh2);

  if (ws_size >= need32) {
    gemm_xp<float><<<dim3(8, 512), 256, 0, stream>>>(x, Wx2, bias, (float*)xpmem);
    lstm_rec<float><<<64, 512, 0, stream>>>(Wh2, (const float*)xpmem, out);
  } else {
    gemm_xp<unsigned short><<<dim3(8, 512), 256, 0, stream>>>(x, Wx2, bias,
                                                              (unsigned short*)xpmem);
    lstm_rec<unsigned short><<<64, 512, 0, stream>>>(Wh2, (const unsigned short*)xpmem, out);
  }
}

// Round 21
// 2105.637 us; speedup vs baseline: 2.9593x; 2.9593x over previous
//
#include <hip/hip_runtime.h>

typedef __attribute__((ext_vector_type(8))) short short8;
typedef __attribute__((ext_vector_type(4))) float f32x4;
typedef __attribute__((ext_vector_type(4))) unsigned u32x4;

__device__ __forceinline__ unsigned short f2bf(float f) {
  unsigned int u = __float_as_uint(f);
  u = (u + 0x7fffu + ((u >> 16) & 1u)) >> 16;
  return (unsigned short)u;
}

__device__ __forceinline__ void xp_store(float* p, float v) { *p = v; }
__device__ __forceinline__ void xp_store(unsigned short* p, float v) { *p = f2bf(v); }
__device__ __forceinline__ float xp_ld(const float* p) { return *p; }
__device__ __forceinline__ float xp_ld(const unsigned short* p) {
  return __uint_as_float(((unsigned int)*p) << 16);
}

// quad reduce via DPP (VALU pipe, no DS): sum over the 4 lanes of each quad.
__device__ __forceinline__ float quad_sum(float a) {
  float t1 = __int_as_float(
      __builtin_amdgcn_update_dpp(0, __float_as_int(a), 177, 0xf, 0xf, true));
  a += t1;
  float t2 = __int_as_float(
      __builtin_amdgcn_update_dpp(0, __float_as_int(a), 78, 0xf, 0xf, true));
  return a + t2;
}

// ---------------- prep: pack W_x and W_h (f32 -> bf16 pairs) ----------------
__global__ void prep_wx(const float* __restrict__ W, unsigned int* __restrict__ Wx2) {
  int i = blockIdx.x * 256 + threadIdx.x;  // 1024*128 dwords
  int g = i >> 7, kk = i & 127;
  float lo = W[(size_t)g * 512 + 256 + 2 * kk];
  float hi = W[(size_t)g * 512 + 256 + 2 * kk + 1];
  Wx2[i] = (unsigned int)f2bf(lo) | ((unsigned int)f2bf(hi) << 16);
}

__global__ void prep_wh(const float* __restrict__ W, unsigned int* __restrict__ Wh2) {
  int i = blockIdx.x * 256 + threadIdx.x;  // 1024*128 dwords
  int r = i >> 7, kk = i & 127;
  float lo = W[(size_t)r * 512 + 2 * kk];
  float hi = W[(size_t)r * 512 + 2 * kk + 1];
  Wh2[i] = (unsigned int)f2bf(lo) | ((unsigned int)f2bf(hi) << 16);
}

// ---------------- GEMM: xp[m][g] = sum_k x[m][k] * Wx[g][k] + b[g] ----------------
template <typename XPT>
__global__ __launch_bounds__(256, 4) void gemm_xp(const float* __restrict__ x,
                                                  const unsigned int* __restrict__ Wx2,
                                                  const float* __restrict__ bias,
                                                  XPT* __restrict__ xp) {
  __shared__ unsigned short As[128][40];
  __shared__ unsigned short Bs[128][40];
  const int m0 = blockIdx.y * 128, n0 = blockIdx.x * 128;
  const int tid = threadIdx.x, lane = tid & 63, w = tid >> 6;
  const int wr = w >> 1, wc = w & 1;
  const int r16 = lane & 15, kq = lane >> 4;
  f32x4 acc[4][4];
#pragma unroll
  for (int m = 0; m < 4; m++)
#pragma unroll
    for (int n = 0; n < 4; n++)
#pragma unroll
      for (int j = 0; j < 4; j++) acc[m][n][j] = 0.f;

  for (int kb = 0; kb < 256; kb += 32) {
    __syncthreads();
#pragma unroll
    for (int i = 0; i < 4; i++) {
      int idx = tid + i * 256;
      int row = idx >> 3, c4 = idx & 7;
      float4 v = *(const float4*)(x + (size_t)(m0 + row) * 256 + kb + c4 * 4);
      ushort4 s;
      s.x = f2bf(v.x); s.y = f2bf(v.y); s.z = f2bf(v.z); s.w = f2bf(v.w);
      *(ushort4*)&As[row][c4 * 4] = s;
    }
#pragma unroll
    for (int i = 0; i < 2; i++) {
      int idx = tid + i * 256;
      int row = idx >> 2, c = idx & 3;
      uint4 v = *(const uint4*)(Wx2 + (size_t)(n0 + row) * 128 + (kb >> 1) + c * 4);
      *(uint4*)&Bs[row][c * 8] = v;
    }
    __syncthreads();
    short8 a[4], bb[4];
#pragma unroll
    for (int m = 0; m < 4; m++)
      a[m] = *(const short8*)&As[wr * 64 + m * 16 + r16][kq * 8];
#pragma unroll
    for (int n = 0; n < 4; n++)
      bb[n] = *(const short8*)&Bs[wc * 64 + n * 16 + r16][kq * 8];
#pragma unroll
    for (int m = 0; m < 4; m++)
#pragma unroll
      for (int n = 0; n < 4; n++)
        acc[m][n] = __builtin_amdgcn_mfma_f32_16x16x32_bf16(a[m], bb[n], acc[m][n], 0, 0, 0);
  }
#pragma unroll
  for (int n = 0; n < 4; n++) {
    int gn = n0 + wc * 64 + n * 16 + r16;
    float bi = bias[gn];
#pragma unroll
    for (int m = 0; m < 4; m++) {
      int gm = m0 + wr * 64 + m * 16 + kq * 4;
#pragma unroll
      for (int j = 0; j < 4; j++) {
        xp_store(&xp[(size_t)(gm + j) * 1024 + gn], acc[m][n][j] + bi);
      }
    }
  }
}

// ---------------- recurrence: 512 threads x 256-VGPR budget, 2 units/thread --------
// FINAL: exact R16/R19 structure (best verified: lstm_rec ~2016us, absmax 0.0078).
// 20-round ledger: inter-CU exchange ~4us/step (R1-R7); in-CU variants all 2.0-2.7
// us/step -- conflicts 33M->0 null (R10), DS-inst cuts null (R13/14), barrier-drain
// removal null (R14), explicit pipelining null (R15), wave halving -7% = this kernel
// (R16), MFMA swap -32% (R17), o-cache correctness cliff (R18), L2-streaming -3x
// (R20). Step is bound by the serial chain {h ds_write -> 8-wave barrier ->
// ds_read latency -> 256 dot2/thread -> transcendental gate math}; no pipe
// saturated (VALU 20%, HBM 0.9%, MFMA 0, conflicts 0) -> latency floor of the
// design space; both alternatives to every link measured worse.
// Thread (v=tid>>2, p=tid&3) owns units (v, v+128) x 4 gates over k-slice
// [p*64,p*64+64). f,i,g rows of both units = 192 dw register-resident (asm-volatile
// loads, unified VGPR/AGPR); o-rows (64 dw) stream from LDS wot[16][512] col-major.
// h: bf16 pairs, 2 slots x 4 p-copies stride 136 (conflict-free); DPP quad reduce;
// raw barrier {lgkmcnt(0); s_barrier}; xp direct from global.
template <typename XPT>
__global__ __attribute__((amdgpu_flat_work_group_size(512, 512),
                          amdgpu_waves_per_eu(2, 2)))
void lstm_rec(const unsigned* __restrict__ Wh2,
              const XPT* __restrict__ xp,
              float* __restrict__ out) {
  __shared__ u32x4 wot[16 * 512];          // 131072B: o-rows of units v / v+128
  __shared__ unsigned hsh[2][4][136];      // 4352B: h bf16-pairs, 2 slots x 4 p-copies

  const int tid = threadIdx.x;
  const int b = blockIdx.x;
  const int v = tid >> 2, p = tid & 3;
  const int brow0 = b << 10;

  // ---- weight register loads: f,i,g rows of units v and v+128 (192 dwords)
  const unsigned* fA_p = Wh2 + (size_t)(v) * 128 + (p << 5);
  const unsigned* iA_p = Wh2 + (size_t)(256 + v) * 128 + (p << 5);
  const unsigned* gA_p = Wh2 + (size_t)(512 + v) * 128 + (p << 5);
  const unsigned* oA_p = Wh2 + (size_t)(768 + v) * 128 + (p << 5);
  const unsigned* fB_p = Wh2 + (size_t)(128 + v) * 128 + (p << 5);
  const unsigned* iB_p = Wh2 + (size_t)(384 + v) * 128 + (p << 5);
  const unsigned* gB_p = Wh2 + (size_t)(640 + v) * 128 + (p << 5);
  const unsigned* oB_p = Wh2 + (size_t)(896 + v) * 128 + (p << 5);
  u32x4 fA0, fA1, fA2, fA3, fA4, fA5, fA6, fA7;
  u32x4 iA0, iA1, iA2, iA3, iA4, iA5, iA6, iA7;
  u32x4 gA0, gA1, gA2, gA3, gA4, gA5, gA6, gA7;
  u32x4 fB0, fB1, fB2, fB3, fB4, fB5, fB6, fB7;
  u32x4 iB0, iB1, iB2, iB3, iB4, iB5, iB6, iB7;
  u32x4 gB0, gB1, gB2, gB3, gB4, gB5, gB6, gB7;
#define LOADROW8(P, R0, R1, R2, R3, R4, R5, R6, R7)                   \
  asm volatile("global_load_dwordx4 %0, %8, off\n\t"                  \
               "global_load_dwordx4 %1, %8, off offset:16\n\t"        \
               "global_load_dwordx4 %2, %8, off offset:32\n\t"        \
               "global_load_dwordx4 %3, %8, off offset:48\n\t"        \
               "global_load_dwordx4 %4, %8, off offset:64\n\t"        \
               "global_load_dwordx4 %5, %8, off offset:80\n\t"        \
               "global_load_dwordx4 %6, %8, off offset:96\n\t"        \
               "global_load_dwordx4 %7, %8, off offset:112"           \
               : "=&v"(R0), "=&v"(R1), "=&v"(R2), "=&v"(R3),          \
                 "=&v"(R4), "=&v"(R5), "=&v"(R6), "=&v"(R7)           \
               : "v"(P)                                               \
               : "memory")
  LOADROW8(fA_p, fA0, fA1, fA2, fA3, fA4, fA5, fA6, fA7);
  LOADROW8(iA_p, iA0, iA1, iA2, iA3, iA4, iA5, iA6, iA7);
  LOADROW8(gA_p, gA0, gA1, gA2, gA3, gA4, gA5, gA6, gA7);
  LOADROW8(fB_p, fB0, fB1, fB2, fB3, fB4, fB5, fB6, fB7);
  LOADROW8(iB_p, iB0, iB1, iB2, iB3, iB4, iB5, iB6, iB7);
  LOADROW8(gB_p, gB0, gB1, gB2, gB3, gB4, gB5, gB6, gB7);
#undef LOADROW8
  asm volatile("s_waitcnt vmcnt(0)" ::: "memory");

  // ---- o-rows -> LDS col-major: chunks E=0..7 unit A, E=8..15 unit B
#pragma unroll
  for (int E = 0; E < 8; E++) {
    wot[(E << 9) + tid] = *(const u32x4*)(oA_p + (E << 2));
    wot[((E + 8) << 9) + tid] = *(const u32x4*)(oB_p + (E << 2));
  }

  // ---- zero both h slots
  for (int i = tid; i < 2 * 4 * 136; i += 512) ((unsigned*)hsh)[i] = 0u;
  float c0 = 0.f, c1 = 0.f;
  float* outp = out + ((size_t)brow0 << 8);
  __syncthreads();  // one full barrier before the loop (covers LDS init)

#define BAR() asm volatile("s_waitcnt lgkmcnt(0)\n\ts_barrier" ::: "memory")
#define DOT2(ACC, WD, HD) \
  asm("v_dot2_f32_bf16 %0, %1, %2, %0" : "+v"(ACC) : "v"(WD), "v"(HD))
// dot one chunk: 2 units x 4 gates x 4 dwords = 32 dot2, all register operands
#define DOTC(FA, IA, GA, FB, IB, GB, OA, OB, HJ)                    \
  {                                                                 \
    DOT2(aF0, FA[0], (HJ)[0]); DOT2(aF0, FA[1], (HJ)[1]);           \
    DOT2(aF0, FA[2], (HJ)[2]); DOT2(aF0, FA[3], (HJ)[3]);           \
    DOT2(aI0, IA[0], (HJ)[0]); DOT2(aI0, IA[1], (HJ)[1]);           \
    DOT2(aI0, IA[2], (HJ)[2]); DOT2(aI0, IA[3], (HJ)[3]);           \
    DOT2(aG0, GA[0], (HJ)[0]); DOT2(aG0, GA[1], (HJ)[1]);           \
    DOT2(aG0, GA[2], (HJ)[2]); DOT2(aG0, GA[3], (HJ)[3]);           \
    DOT2(aO0, (OA)[0], (HJ)[0]); DOT2(aO0, (OA)[1], (HJ)[1]);       \
    DOT2(aO0, (OA)[2], (HJ)[2]); DOT2(aO0, (OA)[3], (HJ)[3]);       \
    DOT2(aF1, FB[0], (HJ)[0]); DOT2(aF1, FB[1], (HJ)[1]);           \
    DOT2(aF1, FB[2], (HJ)[2]); DOT2(aF1, FB[3], (HJ)[3]);           \
    DOT2(aI1, IB[0], (HJ)[0]); DOT2(aI1, IB[1], (HJ)[1]);           \
    DOT2(aI1, IB[2], (HJ)[2]); DOT2(aI1, IB[3], (HJ)[3]);           \
    DOT2(aG1, GB[0], (HJ)[0]); DOT2(aG1, GB[1], (HJ)[1]);           \
    DOT2(aG1, GB[2], (HJ)[2]); DOT2(aG1, GB[3], (HJ)[3]);           \
    DOT2(aO1, (OB)[0], (HJ)[0]); DOT2(aO1, (OB)[1], (HJ)[1]);       \
    DOT2(aO1, (OB)[2], (HJ)[2]); DOT2(aO1, (OB)[3], (HJ)[3]);       \
  }
#define HJC(HRX, J) (*(const u32x4*)&hsh[HRX][p][(p << 5) + ((J) << 2)])

#define LSTM1(AF, AI, AG, AO, X0, X1, X2, X3, CC, HOUT)             \
  {                                                                 \
    float gf = AF + X0, gi = AI + X1, gg = AG + X2, go = AO + X3;   \
    float f = 1.f / (1.f + __expf(-gf));                            \
    float ii = 1.f / (1.f + __expf(-gi));                           \
    float eg = __expf(2.f * gg);                                    \
    float gtv = (eg - 1.f) / (eg + 1.f);                            \
    float o = 1.f / (1.f + __expf(-go));                            \
    CC = f * CC + ii * gtv;                                         \
    float ec = __expf(2.f * CC);                                    \
    float tc = (ec - 1.f) / (ec + 1.f);                             \
    HOUT = o * tc;                                                  \
  }

#define STEP(T, HR, HW)                                                                \
  {                                                                                    \
    const int t = (T);                                                                 \
    /* xp for THIS step: direct global loads (VMEM pipe, consumed at gate add) */      \
    const XPT* xr = xp + ((size_t)(brow0 + t) << 10);                                  \
    float xv0 = xp_ld(xr + v),        xv1 = xp_ld(xr + 256 + v);                       \
    float xv2 = xp_ld(xr + 512 + v),  xv3 = xp_ld(xr + 768 + v);                       \
    float xw0 = xp_ld(xr + 128 + v),  xw1 = xp_ld(xr + 384 + v);                       \
    float xw2 = xp_ld(xr + 640 + v),  xw3 = xp_ld(xr + 896 + v);                       \
    /* depth-2 pipeline over chunks */                                                 \
    u32x4 hX = HJC(HR, 0), oAX = wot[(0 << 9) + tid], oBX = wot[(8 << 9) + tid];       \
    u32x4 hY = HJC(HR, 1), oAY = wot[(1 << 9) + tid], oBY = wot[(9 << 9) + tid];       \
    float aF0 = 0.f, aI0 = 0.f, aG0 = 0.f, aO0 = 0.f;                                  \
    float aF1 = 0.f, aI1 = 0.f, aG1 = 0.f, aO1 = 0.f;                                  \
    DOTC(fA0, iA0, gA0, fB0, iB0, gB0, oAX, oBX, hX)                                   \
    hX = HJC(HR, 2); oAX = wot[(2 << 9) + tid]; oBX = wot[(10 << 9) + tid];            \
    DOTC(fA1, iA1, gA1, fB1, iB1, gB1, oAY, oBY, hY)                                   \
    hY = HJC(HR, 3); oAY = wot[(3 << 9) + tid]; oBY = wot[(11 << 9) + tid];            \
    DOTC(fA2, iA2, gA2, fB2, iB2, gB2, oAX, oBX, hX)                                   \
    hX = HJC(HR, 4); oAX = wot[(4 << 9) + tid]; oBX = wot[(12 << 9) + tid];            \
    DOTC(fA3, iA3, gA3, fB3, iB3, gB3, oAY, oBY, hY)                                   \
    hY = HJC(HR, 5); oAY = wot[(5 << 9) + tid]; oBY = wot[(13 << 9) + tid];            \
    DOTC(fA4, iA4, gA4, fB4, iB4, gB4, oAX, oBX, hX)                                   \
    hX = HJC(HR, 6); oAX = wot[(6 << 9) + tid]; oBX = wot[(14 << 9) + tid];            \
    DOTC(fA5, iA5, gA5, fB5, iB5, gB5, oAY, oBY, hY)                                   \
    hY = HJC(HR, 7); oAY = wot[(7 << 9) + tid]; oBY = wot[(15 << 9) + tid];            \
    DOTC(fA6, iA6, gA6, fB6, iB6, gB6, oAX, oBX, hX)                                   \
    DOTC(fA7, iA7, gA7, fB7, iB7, gB7, oAY, oBY, hY)                                   \
    /* reduce over the 4 p-lanes: DPP quad_perm adds (VALU pipe, no DS) */             \
    aF0 = quad_sum(aF0); aI0 = quad_sum(aI0); aG0 = quad_sum(aG0); aO0 = quad_sum(aO0);\
    aF1 = quad_sum(aF1); aI1 = quad_sum(aI1); aG1 = quad_sum(aG1); aO1 = quad_sum(aO1);\
    float h0v, h1v;                                                                    \
    LSTM1(aF0, aI0, aG0, aO0, xv0, xv1, xv2, xv3, c0, h0v)                             \
    LSTM1(aF1, aI1, aG1, aO1, xw0, xw1, xw2, xw3, c1, h1v)                             \
    /* publish: each lane writes both units' bf16 into its own p-copy */               \
    ((unsigned short*)&hsh[HW][p][0])[v] = f2bf(h0v);                                  \
    ((unsigned short*)&hsh[HW][p][0])[v + 128] = f2bf(h1v);                            \
    if (p == 0) {                                                                      \
      __builtin_nontemporal_store(h0v, outp + ((size_t)t << 8) + v);                   \
      __builtin_nontemporal_store(h1v, outp + ((size_t)t << 8) + v + 128);             \
      if (t == 1023) {                                                                 \
        out[16777216 + b * 256 + v] = h0v;                                             \
        out[16777216 + b * 256 + v + 128] = h1v;                                       \
        out[16777216 + 16384 + b * 256 + v] = c0;                                      \
        out[16777216 + 16384 + b * 256 + v + 128] = c1;                                \
      }                                                                                \
    }                                                                                  \
    /* raw barrier: LDS ordering only -- no vmcnt drain of out-store/xp loads */       \
    BAR();                                                                             \
  }

  for (int t2 = 0; t2 < 1024; t2 += 2) {
    STEP(t2, 1, 0)      // t even: read h slot1, write slot0
    STEP(t2 + 1, 0, 1)  // t odd:  read h slot0, write slot1
  }
#undef STEP
#undef LSTM1
#undef HJC
#undef DOTC
#undef DOT2
#undef BAR
}

extern "C" void kernel_launch(void* const* d_in, const int* in_sizes, int n_in,
                              void* d_out, int out_size, void* d_ws, size_t ws_size,
                              hipStream_t stream) {
  (void)in_sizes; (void)n_in; (void)out_size;
  const float* x = (const float*)d_in[0];
  const float* W = (const float*)d_in[1];
  const float* bias = (const float*)d_in[2];
  float* out = (float*)d_out;
  char* ws = (char*)d_ws;

  unsigned int* Wx2 = (unsigned int*)ws;              // 524288 B
  unsigned int* Wh2 = (unsigned int*)(ws + 524288);   // 524288 B
  char* xpmem = ws + 1048576;

  const size_t need32 = 1048576 + (size_t)65536 * 1024 * 4;

  prep_wx<<<512, 256, 0, stream>>>(W, Wx2);
  prep_wh<<<512, 256, 0, stream>>>(W, Wh2);

  if (ws_size >= need32) {
    gemm_xp<float><<<dim3(8, 512), 256, 0, stream>>>(x, Wx2, bias, (float*)xpmem);
    lstm_rec<float><<<64, 512, 0, stream>>>(Wh2, (const float*)xpmem, out);
  } else {
    gemm_xp<unsigned short><<<dim3(8, 512), 256, 0, stream>>>(x, Wx2, bias,
                                                              (unsigned short*)xpmem);
    lstm_rec<unsigned short><<<64, 512, 0, stream>>>(Wh2, (const unsigned short*)xpmem, out);
  }
}